// Round 3
// baseline (51.300 us; speedup 1.0000x reference)
//
#include <hip/hip_runtime.h>
#include <math.h>

#define HH 128   // hidden size
#define SS 1000  // sequence length
#define NT 1024  // threads per block (16 waves)
#define NW (NT / 64)

#define C1 2.8853900817779268f  // 2*log2(e)
#define C2 1.4426950408889634f  // log2(e)

// ws layout (floats):
//   [0..128)     a0*C1      (W1 @ enc_s_w[:,0], scaled)
//   [128..256)   a1*C1
//   [256..384)   ad*C1      (W2 @ (enc_d_w col sum), scaled)
//   [384..512)   v
//   [512..640)   cc*C1             (iter-0 bias)
//   [640..768)   (cc+w3b)*C1       (iter>0 base bias)
//   [768..896)   w30*C1
//   [896..1024)  w31*C1
//   [1024]       sumv*log2(e)
__global__ void sc_precompute(const float* __restrict__ enc_s_w,
                              const float* __restrict__ enc_s_b,
                              const float* __restrict__ enc_d_w,
                              const float* __restrict__ enc_d_b,
                              const float* __restrict__ v,
                              const float* __restrict__ W,
                              float* __restrict__ ws) {
    int h = threadIdx.x;
    if (h >= HH) return;
    const float4* W1 = (const float4*)(W + h * (3 * HH));
    const float4* W2 = (const float4*)(W + h * (3 * HH) + HH);
    const float4* W3 = (const float4*)(W + h * (3 * HH) + 2 * HH);
    const float4* ES = (const float4*)enc_s_w;
    const float4* ED = (const float4*)enc_d_w;
    const float4* SB = (const float4*)enc_s_b;
    const float4* DB = (const float4*)enc_d_b;
    float a0 = 0.f, a1 = 0.f, ad = 0.f, cc = 0.f, w30 = 0.f, w31 = 0.f, w3b = 0.f;
    #pragma unroll 4
    for (int k4 = 0; k4 < HH / 4; ++k4) {
        float4 w1 = W1[k4], w2 = W2[k4], w3 = W3[k4];
        float4 e01 = ES[2 * k4], e23 = ES[2 * k4 + 1];
        float4 d01 = ED[2 * k4], d23 = ED[2 * k4 + 1];
        float4 sb = SB[k4], db = DB[k4];
        a0 = fmaf(w1.x, e01.x, a0); a0 = fmaf(w1.y, e01.z, a0);
        a0 = fmaf(w1.z, e23.x, a0); a0 = fmaf(w1.w, e23.z, a0);
        a1 = fmaf(w1.x, e01.y, a1); a1 = fmaf(w1.y, e01.w, a1);
        a1 = fmaf(w1.z, e23.y, a1); a1 = fmaf(w1.w, e23.w, a1);
        ad = fmaf(w2.x, d01.x + d01.y, ad); ad = fmaf(w2.y, d01.z + d01.w, ad);
        ad = fmaf(w2.z, d23.x + d23.y, ad); ad = fmaf(w2.w, d23.z + d23.w, ad);
        cc = fmaf(w1.x, sb.x, cc); cc = fmaf(w1.y, sb.y, cc);
        cc = fmaf(w1.z, sb.z, cc); cc = fmaf(w1.w, sb.w, cc);
        cc = fmaf(w2.x, db.x, cc); cc = fmaf(w2.y, db.y, cc);
        cc = fmaf(w2.z, db.z, cc); cc = fmaf(w2.w, db.w, cc);
        w30 = fmaf(w3.x, e01.x, w30); w30 = fmaf(w3.y, e01.z, w30);
        w30 = fmaf(w3.z, e23.x, w30); w30 = fmaf(w3.w, e23.z, w30);
        w31 = fmaf(w3.x, e01.y, w31); w31 = fmaf(w3.y, e01.w, w31);
        w31 = fmaf(w3.z, e23.y, w31); w31 = fmaf(w3.w, e23.w, w31);
        w3b = fmaf(w3.x, sb.x, w3b); w3b = fmaf(w3.y, sb.y, w3b);
        w3b = fmaf(w3.z, sb.z, w3b); w3b = fmaf(w3.w, sb.w, w3b);
    }
    ws[h]            = a0 * C1;
    ws[HH + h]       = a1 * C1;
    ws[2 * HH + h]   = ad * C1;
    ws[3 * HH + h]   = v[h];
    ws[4 * HH + h]   = cc * C1;
    ws[5 * HH + h]   = (cc + w3b) * C1;
    ws[6 * HH + h]   = w30 * C1;
    ws[7 * HH + h]   = w31 * C1;
    if (h == 0) {
        const float4* V4 = (const float4*)v;
        float s = 0.f;
        #pragma unroll 4
        for (int k = 0; k < HH / 4; ++k) { float4 t = V4[k]; s += t.x + t.y + t.z + t.w; }
        ws[8 * HH] = s * C2;
    }
}

// acc = sum_h v[h] * rcp(1 + exp2(z_scaled[h]));  logit = sumv - 2*acc.
// All constant streams are wave-uniform -> compiler scalarizes to s_load;
// x0/x1/yv/X0/X1 live in VGPRs; each fma uses at most 1 SGPR operand.
template <bool FIRST>
__device__ __forceinline__ float sig_acc(const float* __restrict__ ws,
                                         float x0, float x1, float yv,
                                         float X0, float X1) {
    const float4* A0 = (const float4*)(ws);
    const float4* A1 = (const float4*)(ws + HH);
    const float4* AD = (const float4*)(ws + 2 * HH);
    const float4* VV = (const float4*)(ws + 3 * HH);
    const float4* CC = (const float4*)(ws + (FIRST ? 4 * HH : 5 * HH));
    const float4* W0 = (const float4*)(ws + 6 * HH);
    const float4* W1 = (const float4*)(ws + 7 * HH);
    float acc = 0.f;
    #pragma unroll 2
    for (int j = 0; j < HH / 4; ++j) {
        float4 cg = CC[j];
        float b0 = cg.x, b1 = cg.y, b2 = cg.z, b3 = cg.w;
        if (!FIRST) {
            float4 w0 = W0[j], w1 = W1[j];
            b0 = fmaf(w0.x, X0, fmaf(w1.x, X1, b0));
            b1 = fmaf(w0.y, X0, fmaf(w1.y, X1, b1));
            b2 = fmaf(w0.z, X0, fmaf(w1.z, X1, b2));
            b3 = fmaf(w0.w, X0, fmaf(w1.w, X1, b3));
        }
        float4 a0 = A0[j], a1 = A1[j], ad = AD[j], vv = VV[j];
        float z0 = fmaf(a0.x, x0, fmaf(a1.x, x1, fmaf(ad.x, yv, b0)));
        float z1 = fmaf(a0.y, x0, fmaf(a1.y, x1, fmaf(ad.y, yv, b1)));
        float z2 = fmaf(a0.z, x0, fmaf(a1.z, x1, fmaf(ad.z, yv, b2)));
        float z3 = fmaf(a0.w, x0, fmaf(a1.w, x1, fmaf(ad.w, yv, b3)));
        float e0 = __builtin_amdgcn_exp2f(z0);
        float e1 = __builtin_amdgcn_exp2f(z1);
        float e2 = __builtin_amdgcn_exp2f(z2);
        float e3 = __builtin_amdgcn_exp2f(z3);
        float r0 = __builtin_amdgcn_rcpf(1.f + e0);
        float r1 = __builtin_amdgcn_rcpf(1.f + e1);
        float r2 = __builtin_amdgcn_rcpf(1.f + e2);
        float r3 = __builtin_amdgcn_rcpf(1.f + e3);
        acc = fmaf(vv.x, r0, acc);
        acc = fmaf(vv.y, r1, acc);
        acc = fmaf(vv.z, r2, acc);
        acc = fmaf(vv.w, r3, acc);
    }
    return acc;
}

__global__ __launch_bounds__(NT) void sc_main(
    const float* __restrict__ stat, const float* __restrict__ dyn,
    const float* __restrict__ ws,
    const float* __restrict__ enc_s_w, const float* __restrict__ enc_s_b,
    const float* __restrict__ dense_w, const float* __restrict__ dense_b,
    const float* __restrict__ lin_w, const float* __restrict__ lin_b,
    float* __restrict__ out) {
    const int b    = blockIdx.x;
    const int t    = threadIdx.x;
    const int wave = t >> 6;
    const int lane = t & 63;

    __shared__ float4 red4[2][NW];
    __shared__ __align__(16) float hy_sh[HH];

    const float svc2 = ws[8 * HH];

    const bool valid = (t < SS);
    float x0 = 0.f, x1 = 0.f, yv = 0.f;
    if (valid) {
        const float* sb = stat + (size_t)b * 2 * SS;
        x0 = sb[t];
        x1 = sb[SS + t];
        yv = dyn[(size_t)b * 2 * SS + SS + t];
    }

    float X0 = 0.f, X1 = 0.f;

    auto reduce3 = [&](float acc, int parity) {
        float p = valid ? __builtin_amdgcn_exp2f(fmaf(-C1, acc, svc2)) : 0.f;
        float s0 = p, s1 = p * x0, s2 = p * x1;
        #pragma unroll
        for (int off = 32; off > 0; off >>= 1) {
            s0 += __shfl_xor(s0, off);
            s1 += __shfl_xor(s1, off);
            s2 += __shfl_xor(s2, off);
        }
        if (lane == 0) red4[parity][wave] = make_float4(s0, s1, s2, 0.f);
        __syncthreads();  // only barrier per iteration
        float4 w4 = red4[parity][lane & 15];
        #pragma unroll
        for (int off = 1; off < 16; off <<= 1) {
            w4.x += __shfl_xor(w4.x, off);
            w4.y += __shfl_xor(w4.y, off);
            w4.z += __shfl_xor(w4.z, off);
        }
        float inv = __builtin_amdgcn_rcpf(w4.x);
        X0 = w4.y * inv;  // uniform across block by construction
        X1 = w4.z * inv;
    };

    reduce3(sig_acc<true>(ws, x0, x1, yv, 0.f, 0.f), 0);
    reduce3(sig_acc<false>(ws, x0, x1, yv, X0, X1), 1);
    reduce3(sig_acc<false>(ws, x0, x1, yv, X0, X1), 0);

    // hy[h] = enc_s_w[h,0]*X0 + enc_s_w[h,1]*X1 + enc_s_b[h]
    if (t < HH)
        hy_sh[t] = fmaf(enc_s_w[2 * t], X0, fmaf(enc_s_w[2 * t + 1], X1, enc_s_b[t]));
    __syncthreads();

    // out[b] = lin_w @ relu(dense_w @ hy + dense_b) + lin_b
    float o = 0.f;
    if (t < HH) {
        const float4* dw4 = (const float4*)(dense_w + t * HH);
        const float4* hy4 = (const float4*)hy_sh;
        float r = dense_b[t];
        #pragma unroll 4
        for (int k = 0; k < HH / 4; ++k) {
            float4 d4 = dw4[k], h4 = hy4[k];
            r = fmaf(d4.x, h4.x, fmaf(d4.y, h4.y, fmaf(d4.z, h4.z, fmaf(d4.w, h4.w, r))));
        }
        o = lin_w[t] * fmaxf(r, 0.f);
    }
    #pragma unroll
    for (int off = 32; off > 0; off >>= 1) o += __shfl_xor(o, off);
    if (lane == 0) red4[0][wave].x = o;
    __syncthreads();
    if (t == 0) {
        float s = 0.f;
        for (int i = 0; i < NW; ++i) s += red4[0][i].x;
        out[b] = s + lin_b[0];
    }
}

extern "C" void kernel_launch(void* const* d_in, const int* in_sizes, int n_in,
                              void* d_out, int out_size, void* d_ws, size_t ws_size,
                              hipStream_t stream) {
    const float* stat    = (const float*)d_in[0];
    const float* dyn     = (const float*)d_in[1];
    const float* enc_s_w = (const float*)d_in[2];
    const float* enc_s_b = (const float*)d_in[3];
    const float* enc_d_w = (const float*)d_in[4];
    const float* enc_d_b = (const float*)d_in[5];
    const float* v       = (const float*)d_in[6];
    const float* W       = (const float*)d_in[7];
    const float* dense_w = (const float*)d_in[8];
    const float* dense_b = (const float*)d_in[9];
    const float* lin_w   = (const float*)d_in[10];
    const float* lin_b   = (const float*)d_in[11];
    float* out = (float*)d_out;
    float* ws  = (float*)d_ws;

    const int B = in_sizes[0] / (2 * SS);

    hipLaunchKernelGGL(sc_precompute, dim3(1), dim3(HH), 0, stream,
                       enc_s_w, enc_s_b, enc_d_w, enc_d_b, v, W, ws);
    hipLaunchKernelGGL(sc_main, dim3(B), dim3(NT), 0, stream,
                       stat, dyn, ws, enc_s_w, enc_s_b, dense_w, dense_b,
                       lin_w, lin_b, out);
}

// Round 4
// 48.521 us; speedup vs baseline: 1.0573x; 1.0573x over previous
//
#include <hip/hip_runtime.h>
#include <math.h>

#define HH 128   // hidden size
#define SS 1000  // sequence length
#define NT 1024  // threads per block (16 waves)
#define NW (NT / 64)

#define C1 2.8853900817779268f  // 2*log2(e)
#define C2 1.4426950408889634f  // log2(e)

// ws layout (floats):
//   [0..128)     a0*C1      (W1 @ enc_s_w[:,0], scaled)
//   [128..256)   a1*C1
//   [256..384)   ad*C1      (W2 @ (enc_d_w col sum), scaled)
//   [384..512)   v
//   [512..640)   cc*C1             (iter-0 bias)
//   [640..768)   (cc+w3b)*C1       (iter>0 base bias)
//   [768..896)   w30*C1
//   [896..1024)  w31*C1
//   [1024]       sumv*log2(e)
__global__ void sc_precompute(const float* __restrict__ enc_s_w,
                              const float* __restrict__ enc_s_b,
                              const float* __restrict__ enc_d_w,
                              const float* __restrict__ enc_d_b,
                              const float* __restrict__ v,
                              const float* __restrict__ W,
                              float* __restrict__ ws) {
    int h = threadIdx.x;
    if (h >= HH) return;
    const float4* W1 = (const float4*)(W + h * (3 * HH));
    const float4* W2 = (const float4*)(W + h * (3 * HH) + HH);
    const float4* W3 = (const float4*)(W + h * (3 * HH) + 2 * HH);
    const float4* ES = (const float4*)enc_s_w;
    const float4* ED = (const float4*)enc_d_w;
    const float4* SB = (const float4*)enc_s_b;
    const float4* DB = (const float4*)enc_d_b;
    float a0 = 0.f, a1 = 0.f, ad = 0.f, cc = 0.f, w30 = 0.f, w31 = 0.f, w3b = 0.f;
    #pragma unroll 4
    for (int k4 = 0; k4 < HH / 4; ++k4) {
        float4 w1 = W1[k4], w2 = W2[k4], w3 = W3[k4];
        float4 e01 = ES[2 * k4], e23 = ES[2 * k4 + 1];
        float4 d01 = ED[2 * k4], d23 = ED[2 * k4 + 1];
        float4 sb = SB[k4], db = DB[k4];
        a0 = fmaf(w1.x, e01.x, a0); a0 = fmaf(w1.y, e01.z, a0);
        a0 = fmaf(w1.z, e23.x, a0); a0 = fmaf(w1.w, e23.z, a0);
        a1 = fmaf(w1.x, e01.y, a1); a1 = fmaf(w1.y, e01.w, a1);
        a1 = fmaf(w1.z, e23.y, a1); a1 = fmaf(w1.w, e23.w, a1);
        ad = fmaf(w2.x, d01.x + d01.y, ad); ad = fmaf(w2.y, d01.z + d01.w, ad);
        ad = fmaf(w2.z, d23.x + d23.y, ad); ad = fmaf(w2.w, d23.z + d23.w, ad);
        cc = fmaf(w1.x, sb.x, cc); cc = fmaf(w1.y, sb.y, cc);
        cc = fmaf(w1.z, sb.z, cc); cc = fmaf(w1.w, sb.w, cc);
        cc = fmaf(w2.x, db.x, cc); cc = fmaf(w2.y, db.y, cc);
        cc = fmaf(w2.z, db.z, cc); cc = fmaf(w2.w, db.w, cc);
        w30 = fmaf(w3.x, e01.x, w30); w30 = fmaf(w3.y, e01.z, w30);
        w30 = fmaf(w3.z, e23.x, w30); w30 = fmaf(w3.w, e23.z, w30);
        w31 = fmaf(w3.x, e01.y, w31); w31 = fmaf(w3.y, e01.w, w31);
        w31 = fmaf(w3.z, e23.y, w31); w31 = fmaf(w3.w, e23.w, w31);
        w3b = fmaf(w3.x, sb.x, w3b); w3b = fmaf(w3.y, sb.y, w3b);
        w3b = fmaf(w3.z, sb.z, w3b); w3b = fmaf(w3.w, sb.w, w3b);
    }
    ws[h]            = a0 * C1;
    ws[HH + h]       = a1 * C1;
    ws[2 * HH + h]   = ad * C1;
    ws[3 * HH + h]   = v[h];
    ws[4 * HH + h]   = cc * C1;
    ws[5 * HH + h]   = (cc + w3b) * C1;
    ws[6 * HH + h]   = w30 * C1;
    ws[7 * HH + h]   = w31 * C1;
    if (h == 0) {
        const float4* V4 = (const float4*)v;
        float s = 0.f;
        #pragma unroll 4
        for (int k = 0; k < HH / 4; ++k) { float4 t = V4[k]; s += t.x + t.y + t.z + t.w; }
        ws[8 * HH] = s * C2;
    }
}

// DPP row_shr:N add — reduces within each 16-lane row toward lane 15. VALU-only.
template <int CTRL>
__device__ __forceinline__ float dpp_add(float x) {
    int s = __builtin_amdgcn_update_dpp(0, __builtin_bit_cast(int, x),
                                        CTRL, 0xF, 0xF, true);
    return x + __builtin_bit_cast(float, s);
}

__global__ __launch_bounds__(NT) void sc_main(
    const float* __restrict__ stat, const float* __restrict__ dyn,
    const float* __restrict__ ws,
    const float* __restrict__ enc_s_w, const float* __restrict__ enc_s_b,
    const float* __restrict__ dense_w, const float* __restrict__ dense_b,
    const float* __restrict__ lin_w, const float* __restrict__ lin_b,
    float* __restrict__ out) {
    const int b    = blockIdx.x;
    const int t    = threadIdx.x;
    const int wave = t >> 6;
    const int lane = t & 63;
    const int g    = t & 15;   // h-slice index: h = 8g .. 8g+7
    const int sg   = t >> 4;   // s-group 0..63; s = pass*64 + sg

    __shared__ __align__(16) float4 xs[NT];      // {x0, x1, yv, 0} per s
    __shared__ float4 red4[2][NW];
    __shared__ __align__(16) float hy_sh[HH];

    // ---- stage per-s inputs to LDS (coalesced) ----
    {
        float x0 = 0.f, x1 = 0.f, yv = 0.f;
        if (t < SS) {
            const float* sb = stat + (size_t)b * 2 * SS;
            x0 = sb[t];
            x1 = sb[SS + t];
            yv = dyn[(size_t)b * 2 * SS + SS + t];
        }
        xs[t] = make_float4(x0, x1, yv, 0.f);
    }

    // ---- per-thread register-resident constants: 8 streams x 8 h ----
    const int h0 = g * 8;
    float a0[8], a1[8], ad[8], vv[8], c0[8], cb[8], w0[8], w1[8];
    *(float4*)&a0[0] = *(const float4*)(ws + h0);
    *(float4*)&a0[4] = *(const float4*)(ws + h0 + 4);
    *(float4*)&a1[0] = *(const float4*)(ws + HH + h0);
    *(float4*)&a1[4] = *(const float4*)(ws + HH + h0 + 4);
    *(float4*)&ad[0] = *(const float4*)(ws + 2 * HH + h0);
    *(float4*)&ad[4] = *(const float4*)(ws + 2 * HH + h0 + 4);
    *(float4*)&vv[0] = *(const float4*)(ws + 3 * HH + h0);
    *(float4*)&vv[4] = *(const float4*)(ws + 3 * HH + h0 + 4);
    *(float4*)&c0[0] = *(const float4*)(ws + 4 * HH + h0);
    *(float4*)&c0[4] = *(const float4*)(ws + 4 * HH + h0 + 4);
    *(float4*)&cb[0] = *(const float4*)(ws + 5 * HH + h0);
    *(float4*)&cb[4] = *(const float4*)(ws + 5 * HH + h0 + 4);
    *(float4*)&w0[0] = *(const float4*)(ws + 6 * HH + h0);
    *(float4*)&w0[4] = *(const float4*)(ws + 6 * HH + h0 + 4);
    *(float4*)&w1[0] = *(const float4*)(ws + 7 * HH + h0);
    *(float4*)&w1[4] = *(const float4*)(ws + 7 * HH + h0 + 4);
    const float svc2 = ws[8 * HH];

    __syncthreads();  // xs ready

    float X0 = 0.f, X1 = 0.f;

    for (int iter = 0; iter < 3; ++iter) {
        float cg[8];
        #pragma unroll
        for (int i = 0; i < 8; ++i)
            cg[i] = (iter == 0) ? c0[i] : fmaf(w0[i], X0, fmaf(w1[i], X1, cb[i]));

        float S = 0.f, Sx0 = 0.f, Sx1 = 0.f;
        for (int pass = 0; pass < 16; ++pass) {
            const int s = pass * 64 + sg;
            float4 x = xs[s];
            float acc = 0.f;
            #pragma unroll
            for (int i = 0; i < 8; ++i) {
                float z = fmaf(a0[i], x.x, fmaf(a1[i], x.y, fmaf(ad[i], x.z, cg[i])));
                float e = __builtin_amdgcn_exp2f(z);
                acc = fmaf(vv[i], __builtin_amdgcn_rcpf(1.f + e), acc);
            }
            // reduce acc over the 16-lane h-group -> lane g==15 holds total
            acc = dpp_add<0x118>(acc);  // row_shr:8
            acc = dpp_add<0x114>(acc);  // row_shr:4
            acc = dpp_add<0x112>(acc);  // row_shr:2
            acc = dpp_add<0x111>(acc);  // row_shr:1
            const bool own = (g == 15) && (s < SS);
            float arg = own ? fmaf(-C1, acc, svc2) : -128.f;  // exp2(-128)=0
            float p = __builtin_amdgcn_exp2f(arg);
            S   += p;
            Sx0  = fmaf(p, x.x, Sx0);
            Sx1  = fmaf(p, x.y, Sx1);
        }

        // wave reduce (owners at lanes 15,31,47,63)
        S   += __shfl_xor(S, 16);   S   += __shfl_xor(S, 32);
        Sx0 += __shfl_xor(Sx0, 16); Sx0 += __shfl_xor(Sx0, 32);
        Sx1 += __shfl_xor(Sx1, 16); Sx1 += __shfl_xor(Sx1, 32);
        if (lane == 15) red4[iter & 1][wave] = make_float4(S, Sx0, Sx1, 0.f);
        __syncthreads();  // only barrier per iteration

        float4 w4 = red4[iter & 1][lane & 15];
        #pragma unroll
        for (int off = 1; off < 16; off <<= 1) {
            w4.x += __shfl_xor(w4.x, off);
            w4.y += __shfl_xor(w4.y, off);
            w4.z += __shfl_xor(w4.z, off);
        }
        float inv = __builtin_amdgcn_rcpf(w4.x);
        X0 = w4.y * inv;  // uniform across block
        X1 = w4.z * inv;
    }

    // hy[h] = enc_s_w[h,0]*X0 + enc_s_w[h,1]*X1 + enc_s_b[h]
    if (t < HH)
        hy_sh[t] = fmaf(enc_s_w[2 * t], X0, fmaf(enc_s_w[2 * t + 1], X1, enc_s_b[t]));
    __syncthreads();

    // out[b] = lin_w @ relu(dense_w @ hy + dense_b) + lin_b
    float o = 0.f;
    if (t < HH) {
        const float4* dw4 = (const float4*)(dense_w + t * HH);
        const float4* hy4 = (const float4*)hy_sh;
        float r = dense_b[t];
        #pragma unroll 4
        for (int k = 0; k < HH / 4; ++k) {
            float4 d4 = dw4[k], h4 = hy4[k];
            r = fmaf(d4.x, h4.x, fmaf(d4.y, h4.y, fmaf(d4.z, h4.z, fmaf(d4.w, h4.w, r))));
        }
        o = lin_w[t] * fmaxf(r, 0.f);
    }
    #pragma unroll
    for (int off = 32; off > 0; off >>= 1) o += __shfl_xor(o, off);
    if (lane == 0) red4[0][wave].x = o;
    __syncthreads();
    if (t == 0) {
        float s = 0.f;
        for (int i = 0; i < NW; ++i) s += red4[0][i].x;
        out[b] = s + lin_b[0];
    }
}

extern "C" void kernel_launch(void* const* d_in, const int* in_sizes, int n_in,
                              void* d_out, int out_size, void* d_ws, size_t ws_size,
                              hipStream_t stream) {
    const float* stat    = (const float*)d_in[0];
    const float* dyn     = (const float*)d_in[1];
    const float* enc_s_w = (const float*)d_in[2];
    const float* enc_s_b = (const float*)d_in[3];
    const float* enc_d_w = (const float*)d_in[4];
    const float* enc_d_b = (const float*)d_in[5];
    const float* v       = (const float*)d_in[6];
    const float* W       = (const float*)d_in[7];
    const float* dense_w = (const float*)d_in[8];
    const float* dense_b = (const float*)d_in[9];
    const float* lin_w   = (const float*)d_in[10];
    const float* lin_b   = (const float*)d_in[11];
    float* out = (float*)d_out;
    float* ws  = (float*)d_ws;

    const int B = in_sizes[0] / (2 * SS);

    hipLaunchKernelGGL(sc_precompute, dim3(1), dim3(HH), 0, stream,
                       enc_s_w, enc_s_b, enc_d_w, enc_d_b, v, W, ws);
    hipLaunchKernelGGL(sc_main, dim3(B), dim3(NT), 0, stream,
                       stat, dyn, ws, enc_s_w, enc_s_b, dense_w, dense_b,
                       lin_w, lin_b, out);
}